// Round 3
// baseline (3901.602 us; speedup 1.0000x reference)
//
#include <hip/hip_runtime.h>
#include <cstdint>
#include <cstddef>

typedef unsigned short u16;
typedef short bf16x8 __attribute__((ext_vector_type(8)));
typedef u16   u16x8  __attribute__((ext_vector_type(8)));
typedef float f32x4  __attribute__((ext_vector_type(4)));

#define NT  512
#define NB  64
#define NH  1024
#define NTB 32768   // NT*NB
#define G4  4096

#define AS1C(p) ((const __attribute__((address_space(1))) void*)(p))
#define AS3(p)  ((__attribute__((address_space(3))) void*)(p))

__device__ __forceinline__ float b2f(u16 u){
  return __uint_as_float(((unsigned)u) << 16);
}
__device__ __forceinline__ u16 f2b(float f){
  unsigned u = __float_as_uint(f);
  return (u16)((u + 0x7fffu + ((u >> 16) & 1u)) >> 16);
}
__device__ __forceinline__ float fsigmoid(float x){
  return __builtin_amdgcn_rcpf(1.f + __builtin_amdgcn_exp2f(-1.442695041f * x));
}
__device__ __forceinline__ float ftanh(float x){
  return 2.f * __builtin_amdgcn_rcpf(1.f + __builtin_amdgcn_exp2f(-2.885390082f * x)) - 1.f;
}

// ---------------- f32 -> bf16 conversion ----------------
__global__ void cvt_bf16(const float* __restrict__ in, u16* __restrict__ out, int n8){
  int stride = gridDim.x * blockDim.x;
  for (int i = blockIdx.x * blockDim.x + threadIdx.x; i < n8; i += stride){
    const float4* p = (const float4*)(in + (size_t)i * 8);
    float4 a = p[0], b = p[1];
    u16x8 r;
    r[0]=f2b(a.x); r[1]=f2b(a.y); r[2]=f2b(a.z); r[3]=f2b(a.w);
    r[4]=f2b(b.x); r[5]=f2b(b.y); r[6]=f2b(b.z); r[7]=f2b(b.w);
    *(u16x8*)(out + (size_t)i * 8) = r;
  }
}

// ---------------- z-gate precompute ----------------
__global__ void zpre_kernel(const float* __restrict__ x, const float* __restrict__ Wih,
                            const float* __restrict__ b_ih, const float* __restrict__ b_hh,
                            float* __restrict__ zp){
  int gw   = (blockIdx.x * 256 + threadIdx.x) >> 6;
  int lane = threadIdx.x & 63;
  const float* wz = Wih + (size_t)4096 * 1024;
  float4 wv[4];
  #pragma unroll
  for (int j = 0; j < 4; ++j) wv[j] = *(const float4*)&wz[lane*16 + j*4];
  float bz = b_ih[4096] + b_hh[4096];
  for (int r = gw; r < NTB; r += 1024){
    const float* xr = x + (size_t)r * 1024 + lane * 16;
    float s = 0.f;
    #pragma unroll
    for (int j = 0; j < 4; ++j){
      float4 xv = *(const float4*)&xr[j*4];
      s += xv.x*wv[j].x + xv.y*wv[j].y + xv.z*wv[j].z + xv.w*wv[j].w;
    }
    #pragma unroll
    for (int o = 32; o > 0; o >>= 1) s += __shfl_down(s, o);
    if (lane == 0) zp[r] = s + bz;
  }
}

// ---------------- Phase-1 GEMM: gx[32768,4096] = Xb @ Wb^T + bias ----------------
template<typename GT>
__global__ __launch_bounds__(256, 2) void gemm_gx(
    const u16* __restrict__ Xb, const u16* __restrict__ Wb,
    const float* __restrict__ b_ih, const float* __restrict__ b_hh,
    GT* __restrict__ gx)
{
  __shared__ u16 As[128*32];
  __shared__ u16 Bs[128*32];
  const int tid  = threadIdx.x;
  const int lane = tid & 63, wave = tid >> 6;
  const int wr = wave >> 1, wc = wave & 1;
  const int m0 = (blockIdx.x & 255) * 128;
  const int n0 = (blockIdx.x >> 8) * 128;
  const int srow = wave * 16 + (lane >> 2);
  const int scol = (lane & 3) * 8;
  const u16* gA = Xb + (size_t)(m0 + srow) * 1024 + scol;
  const u16* gB = Wb + (size_t)(n0 + srow) * 1024 + scol;
  char* lA = (char*)As + wave * 1024;
  char* lB = (char*)Bs + wave * 1024;
  const int fr = lane & 15, fo = (lane >> 4) * 8;

  f32x4 acc[4][4] = {};
  for (int k0 = 0; k0 < 1024; k0 += 32){
    __syncthreads();
    __builtin_amdgcn_global_load_lds(AS1C(gA + k0),            AS3(lA),        16, 0, 0);
    __builtin_amdgcn_global_load_lds(AS1C(gA + 64*1024 + k0),  AS3(lA + 4096), 16, 0, 0);
    __builtin_amdgcn_global_load_lds(AS1C(gB + k0),            AS3(lB),        16, 0, 0);
    __builtin_amdgcn_global_load_lds(AS1C(gB + 64*1024 + k0),  AS3(lB + 4096), 16, 0, 0);
    __syncthreads();
    bf16x8 a[4], b[4];
    #pragma unroll
    for (int mi = 0; mi < 4; ++mi)
      a[mi] = *(const bf16x8*)&As[(wr*64 + mi*16 + fr)*32 + fo];
    #pragma unroll
    for (int ni = 0; ni < 4; ++ni)
      b[ni] = *(const bf16x8*)&Bs[(wc*64 + ni*16 + fr)*32 + fo];
    #pragma unroll
    for (int mi = 0; mi < 4; ++mi)
      #pragma unroll
      for (int ni = 0; ni < 4; ++ni)
        acc[mi][ni] = __builtin_amdgcn_mfma_f32_16x16x32_bf16(a[mi], b[ni], acc[mi][ni], 0, 0, 0);
  }
  const int orow = (lane >> 4) * 4, ocol = lane & 15;
  #pragma unroll
  for (int ni = 0; ni < 4; ++ni){
    const int g = n0 + wc*64 + ni*16 + ocol;
    const float bias = b_ih[g] + b_hh[g];
    #pragma unroll
    for (int mi = 0; mi < 4; ++mi){
      const size_t rb = (size_t)(m0 + wr*64 + mi*16 + orow);
      #pragma unroll
      for (int r = 0; r < 4; ++r){
        float v = acc[mi][ni][r] + bias;
        if constexpr (sizeof(GT) == 4)
          __builtin_nontemporal_store(v, (float*)gx + (rb + r)*G4 + g);
        else
          __builtin_nontemporal_store(f2b(v), (u16*)gx + (rb + r)*G4 + g);
      }
    }
  }
}

__device__ __forceinline__ float ld_gx(const float* p){ return __builtin_nontemporal_load(p); }
__device__ __forceinline__ float ld_gx(const u16* p){ return b2f(__builtin_nontemporal_load(p)); }

// ---------------- Phase-2 persistent scan ----------------
// 256 WGs x 256 thr. WG = (mb: batch-group of 16, hb: 16 hidden cols).
// Wave w owns gate w; W_hh slice pinned in regs. h exchanged through L3 via
// ROTATING buffers (h^t at hbase + t*65536, never reused -> readers' L1/L2
// always cold -> plain global_load_lds is coherent). Writers store sc0 sc1
// (bypass to L3). Per-wave flags, polled as dwordx4.
template<typename GT>
__global__ __launch_bounds__(256, 1) void hmlstm_scan(
    const u16* __restrict__ Whh, const GT* __restrict__ gx,
    const float* __restrict__ zpre, u16* __restrict__ hbase,
    float* __restrict__ out, unsigned* __restrict__ bar)
{
  const int tid  = threadIdx.x;
  const int lane = tid & 63, wave = tid >> 6;
  const int wg = blockIdx.x;
  const int mb = wg >> 6, hb = wg & 63;
  const int fr = lane & 15, hi4 = lane >> 4;
  const int b_l = tid >> 4, h_l = tid & 15;
  const int browg = mb*16 + b_l;

  __shared__ u16  hs[16*1024];       // 32KB, XOR-swizzled h tile (swizzle via source addr)
  __shared__ float glds[4][16][16];
  __shared__ float zpart[4][16];
  __shared__ u16  wz[1024];

  ((unsigned long long*)wz)[tid] = ((const unsigned long long*)(Whh + (size_t)4096*1024))[tid];

  // persistent W_hh fragments: gate row = wave*1024 + hb*16 + fr
  const int grow = wave*1024 + hb*16 + fr;
  bf16x8 Bw[32];
  #pragma unroll
  for (int kc = 0; kc < 32; ++kc)
    Bw[kc] = *(const bf16x8*)&Whh[(size_t)grow*1024 + kc*32 + hi4*8];
  #pragma unroll
  for (int kc = 0; kc < 32; ++kc)
    asm volatile("" : "+v"(Bw[kc]));

  // zero h^0 slot through L3
  {
    u16* p = hbase + (size_t)mb*16384 + hb*256 + tid;
    unsigned z = 0;
    asm volatile("global_store_short %0, %1, off sc0 sc1" :: "v"(p), "v"(z) : "memory");
    asm volatile("s_waitcnt vmcnt(0)" ::: "memory");
  }
  unsigned* myflag = bar + mb*256 + hb*4 + wave;
  const unsigned* gflags = bar + mb*256;
  if (lane == 0){
    unsigned one = 1;
    asm volatile("global_store_dword %0, %1, off sc0 sc1" :: "v"(myflag), "v"(one) : "memory");
  }

  float c_reg = 0.f;

  for (int t = 0; t < NT; ++t){
    const u16* hc = hbase + (size_t)t * 65536;
    u16*       hn = hbase + (size_t)(t + 1) * 65536;

    // gx + zpre prefetch (independent of h; absorbed by the poll below)
    float gxl[4];
    const GT* gp = gx + ((size_t)t*64 + mb*16 + hi4*4)*G4 + wave*1024 + hb*16 + fr;
    #pragma unroll
    for (int r = 0; r < 4; ++r) gxl[r] = ld_gx(gp + (size_t)r*G4);
    float zpc = zpre[t*64 + browg];

    // acquire: all 256 wave-flags of this group >= t+1
    {
      const unsigned* fp = gflags + lane*4;
      unsigned tgt = (unsigned)(t + 1);
      uint4 fv;
      unsigned mn;
      do {
        asm volatile("global_load_dwordx4 %0, %1, off sc0 sc1\n\ts_waitcnt vmcnt(0)"
                     : "=v"(fv) : "v"(fp) : "memory");
        mn = min(min(fv.x, fv.y), min(fv.z, fv.w));
      } while (!__all((int)(mn >= tgt)));
      __builtin_amdgcn_sched_barrier(0);
    }

    // stage h^t tile (16x1024 bf16 = 32KB) directly global->LDS.
    // LDS linear; swizzle applied on the SOURCE address (involution), so
    // LDS[row][c16] = G[row][c16 ^ (row&7)].
    {
      const char* gsrc = (const char*)hc + (size_t)mb * 32768;
      char* hsB = (char*)hs;
      #pragma unroll
      for (int j = 0; j < 8; ++j){
        int chunk = wave*8 + j;            // 0..31 (uniform per wave)
        int row   = chunk >> 1;
        int srcoff = row*2048 + ((((chunk & 1)*64 + lane)*16) ^ ((row & 7) << 4));
        __builtin_amdgcn_global_load_lds(AS1C(gsrc + srcoff), AS3(hsB + chunk*1024), 16, 0, 0);
      }
    }
    asm volatile("s_waitcnt vmcnt(0)" ::: "memory");
    __builtin_amdgcn_sched_barrier(0);
    __syncthreads();

    // recurrent GEMM: 16 batches x 16 gate cols, K=1024
    f32x4 acc[4] = {}, az = {};
    #pragma unroll
    for (int kc = 0; kc < 32; ++kc){
      bf16x8 a = *(const bf16x8*)((char*)hs + fr*2048 + ((kc*64 + hi4*16) ^ ((fr&7)<<4)));
      acc[kc & 3] = __builtin_amdgcn_mfma_f32_16x16x32_bf16(a, Bw[kc], acc[kc & 3], 0, 0, 0);
    }
    // z-gate MFMA: wave w covers kc in [w*8, w*8+8)
    #pragma unroll
    for (int q = 0; q < 8; ++q){
      int kcz = wave*8 + q;
      bf16x8 a  = *(const bf16x8*)((char*)hs + fr*2048 + ((kcz*64 + hi4*16) ^ ((fr&7)<<4)));
      bf16x8 bz = *(const bf16x8*)&wz[kcz*32 + hi4*8];
      az = __builtin_amdgcn_mfma_f32_16x16x32_bf16(a, bz, az, 0, 0, 0);
    }
    f32x4 ac = (acc[0] + acc[1]) + (acc[2] + acc[3]);

    // gates -> LDS (wave 2 = tanh, others sigmoid)
    #pragma unroll
    for (int r = 0; r < 4; ++r){
      float v = ac[r] + gxl[r];
      float s = (wave == 2) ? ftanh(v) : fsigmoid(v);
      glds[wave][hi4*4 + r][fr] = s;
    }
    if (fr == 0){
      #pragma unroll
      for (int r = 0; r < 4; ++r) zpart[wave][hi4*4 + r] = az[r];
    }
    __syncthreads();

    // combine: one (batch, hidden) element per thread
    float iv = glds[0][b_l][h_l], fvg = glds[1][b_l][h_l];
    float gv = glds[2][b_l][h_l], ov = glds[3][b_l][h_l];
    float zs = zpart[0][b_l] + zpart[1][b_l] + zpart[2][b_l] + zpart[3][b_l];
    float zv = fsigmoid(zpc + zs);
    float ig = iv * gv;
    float cn = zv*ig + (1.f - zv)*(fvg*c_reg + ig);
    float hv_ = ov * ftanh(cn);
    c_reg = cn;
    const int hoff = browg*1024 + hb*16 + h_l;

    // publish: h store -> ack -> per-wave flag. NOTHING else in this path.
    {
      unsigned hv16 = (unsigned)f2b(hv_);
      asm volatile("global_store_short %0, %1, off sc0 sc1" :: "v"(hn + hoff), "v"(hv16) : "memory");
      asm volatile("s_waitcnt vmcnt(0)" ::: "memory");
      if (lane == 0){
        unsigned pv = (unsigned)(t + 2);
        asm volatile("global_store_dword %0, %1, off sc0 sc1" :: "v"(myflag), "v"(pv) : "memory");
      }
    }

    // off-path stores (fire-and-forget; retired long before next publish)
    __builtin_nontemporal_store(hv_, out + (size_t)t*65536 + hoff);
    if (t == NT-1){
      out[(size_t)NT*65536 + hoff] = hv_;            // hT
      out[(size_t)NT*65536 + 65536 + hoff] = cn;     // cT
    }
  }
}

// ---------------- host ----------------
extern "C" void kernel_launch(void* const* d_in, const int* in_sizes, int n_in,
                              void* d_out, int out_size, void* d_ws, size_t ws_size,
                              hipStream_t stream)
{
  (void)in_sizes; (void)n_in; (void)out_size;
  const float* x    = (const float*)d_in[0];
  const float* Wih  = (const float*)d_in[1];
  const float* Whh  = (const float*)d_in[2];
  const float* b_ih = (const float*)d_in[3];
  const float* b_hh = (const float*)d_in[4];
  float* out = (float*)d_out;

  size_t off = 0;
  auto alloc = [&](size_t bytes)->void*{
    void* p = (char*)d_ws + off;
    off = (off + bytes + 255) & ~(size_t)255;
    return p;
  };
  u16*  xb    = (u16*) alloc((size_t)NTB*1024*2);
  u16*  wihb  = (u16*) alloc((size_t)4097*1024*2);
  u16*  whhb  = (u16*) alloc((size_t)4097*1024*2);
  u16*  hbase = (u16*) alloc((size_t)(NT+1)*65536*2);   // rotating h buffers
  float* zp   = (float*)alloc((size_t)NTB*4);
  unsigned* bar = (unsigned*)alloc(4096);
  bool g32 = (ws_size >= off + (size_t)NTB*G4*4);
  void* gxp = (char*)d_ws + off;

  hipMemsetAsync(bar, 0, 4096, stream);
  cvt_bf16<<<dim3(2048), dim3(256), 0, stream>>>(x,   xb,   NTB*1024/8);
  cvt_bf16<<<dim3(512),  dim3(256), 0, stream>>>(Wih, wihb, 4097*1024/8);
  cvt_bf16<<<dim3(512),  dim3(256), 0, stream>>>(Whh, whhb, 4097*1024/8);
  zpre_kernel<<<dim3(256), dim3(256), 0, stream>>>(x, Wih, b_ih, b_hh, zp);
  if (g32){
    gemm_gx<float><<<dim3(8192), dim3(256), 0, stream>>>(xb, wihb, b_ih, b_hh, (float*)gxp);
    hmlstm_scan<float><<<dim3(256), dim3(256), 0, stream>>>(whhb, (const float*)gxp, zp,
                                                            hbase, out, bar);
  } else {
    gemm_gx<u16><<<dim3(8192), dim3(256), 0, stream>>>(xb, wihb, b_ih, b_hh, (u16*)gxp);
    hmlstm_scan<u16><<<dim3(256), dim3(256), 0, stream>>>(whhb, (const u16*)gxp, zp,
                                                          hbase, out, bar);
  }
}

// Round 5
// 3520.491 us; speedup vs baseline: 1.1083x; 1.1083x over previous
//
#include <hip/hip_runtime.h>
#include <cstdint>
#include <cstddef>

typedef unsigned short u16;
typedef short bf16x8 __attribute__((ext_vector_type(8)));
typedef u16   u16x8  __attribute__((ext_vector_type(8)));
typedef float f32x4  __attribute__((ext_vector_type(4)));

#define NT  512
#define NB  64
#define NH  1024
#define NTB 32768   // NT*NB
#define G4  4096

#define AS1C(p) ((const __attribute__((address_space(1))) void*)(p))
#define AS3(p)  ((__attribute__((address_space(3))) void*)(p))

__device__ __forceinline__ float b2f(u16 u){
  return __uint_as_float(((unsigned)u) << 16);
}
__device__ __forceinline__ u16 f2b(float f){
  unsigned u = __float_as_uint(f);
  return (u16)((u + 0x7fffu + ((u >> 16) & 1u)) >> 16);
}
__device__ __forceinline__ float fsigmoid(float x){
  return __builtin_amdgcn_rcpf(1.f + __builtin_amdgcn_exp2f(-1.442695041f * x));
}
__device__ __forceinline__ float ftanh(float x){
  return 2.f * __builtin_amdgcn_rcpf(1.f + __builtin_amdgcn_exp2f(-2.885390082f * x)) - 1.f;
}

// ---------------- f32 -> bf16 conversion ----------------
__global__ void cvt_bf16(const float* __restrict__ in, u16* __restrict__ out, int n8){
  int stride = gridDim.x * blockDim.x;
  for (int i = blockIdx.x * blockDim.x + threadIdx.x; i < n8; i += stride){
    const float4* p = (const float4*)(in + (size_t)i * 8);
    float4 a = p[0], b = p[1];
    u16x8 r;
    r[0]=f2b(a.x); r[1]=f2b(a.y); r[2]=f2b(a.z); r[3]=f2b(a.w);
    r[4]=f2b(b.x); r[5]=f2b(b.y); r[6]=f2b(b.z); r[7]=f2b(b.w);
    *(u16x8*)(out + (size_t)i * 8) = r;
  }
}

// ---------------- z-gate precompute ----------------
__global__ void zpre_kernel(const float* __restrict__ x, const float* __restrict__ Wih,
                            const float* __restrict__ b_ih, const float* __restrict__ b_hh,
                            float* __restrict__ zp){
  int gw   = (blockIdx.x * 256 + threadIdx.x) >> 6;
  int lane = threadIdx.x & 63;
  const float* wz = Wih + (size_t)4096 * 1024;
  float4 wv[4];
  #pragma unroll
  for (int j = 0; j < 4; ++j) wv[j] = *(const float4*)&wz[lane*16 + j*4];
  float bz = b_ih[4096] + b_hh[4096];
  for (int r = gw; r < NTB; r += 1024){
    const float* xr = x + (size_t)r * 1024 + lane * 16;
    float s = 0.f;
    #pragma unroll
    for (int j = 0; j < 4; ++j){
      float4 xv = *(const float4*)&xr[j*4];
      s += xv.x*wv[j].x + xv.y*wv[j].y + xv.z*wv[j].z + xv.w*wv[j].w;
    }
    #pragma unroll
    for (int o = 32; o > 0; o >>= 1) s += __shfl_down(s, o);
    if (lane == 0) zp[r] = s + bz;
  }
}

// ---------------- Phase-1 GEMM: gx[32768,4096] = Xb @ Wb^T + bias ----------------
template<typename GT>
__global__ __launch_bounds__(256, 2) void gemm_gx(
    const u16* __restrict__ Xb, const u16* __restrict__ Wb,
    const float* __restrict__ b_ih, const float* __restrict__ b_hh,
    GT* __restrict__ gx)
{
  __shared__ u16 As[128*32];
  __shared__ u16 Bs[128*32];
  const int tid  = threadIdx.x;
  const int lane = tid & 63, wave = tid >> 6;
  const int wr = wave >> 1, wc = wave & 1;
  const int m0 = (blockIdx.x & 255) * 128;
  const int n0 = (blockIdx.x >> 8) * 128;
  const int srow = wave * 16 + (lane >> 2);
  const int scol = (lane & 3) * 8;
  const u16* gA = Xb + (size_t)(m0 + srow) * 1024 + scol;
  const u16* gB = Wb + (size_t)(n0 + srow) * 1024 + scol;
  char* lA = (char*)As + wave * 1024;
  char* lB = (char*)Bs + wave * 1024;
  const int fr = lane & 15, fo = (lane >> 4) * 8;

  f32x4 acc[4][4] = {};
  for (int k0 = 0; k0 < 1024; k0 += 32){
    __syncthreads();
    __builtin_amdgcn_global_load_lds(AS1C(gA + k0),            AS3(lA),        16, 0, 0);
    __builtin_amdgcn_global_load_lds(AS1C(gA + 64*1024 + k0),  AS3(lA + 4096), 16, 0, 0);
    __builtin_amdgcn_global_load_lds(AS1C(gB + k0),            AS3(lB),        16, 0, 0);
    __builtin_amdgcn_global_load_lds(AS1C(gB + 64*1024 + k0),  AS3(lB + 4096), 16, 0, 0);
    __syncthreads();
    bf16x8 a[4], b[4];
    #pragma unroll
    for (int mi = 0; mi < 4; ++mi)
      a[mi] = *(const bf16x8*)&As[(wr*64 + mi*16 + fr)*32 + fo];
    #pragma unroll
    for (int ni = 0; ni < 4; ++ni)
      b[ni] = *(const bf16x8*)&Bs[(wc*64 + ni*16 + fr)*32 + fo];
    #pragma unroll
    for (int mi = 0; mi < 4; ++mi)
      #pragma unroll
      for (int ni = 0; ni < 4; ++ni)
        acc[mi][ni] = __builtin_amdgcn_mfma_f32_16x16x32_bf16(a[mi], b[ni], acc[mi][ni], 0, 0, 0);
  }
  const int orow = (lane >> 4) * 4, ocol = lane & 15;
  #pragma unroll
  for (int ni = 0; ni < 4; ++ni){
    const int g = n0 + wc*64 + ni*16 + ocol;
    const float bias = b_ih[g] + b_hh[g];
    #pragma unroll
    for (int mi = 0; mi < 4; ++mi){
      const size_t rb = (size_t)(m0 + wr*64 + mi*16 + orow);
      #pragma unroll
      for (int r = 0; r < 4; ++r){
        float v = acc[mi][ni][r] + bias;
        if constexpr (sizeof(GT) == 4)
          __builtin_nontemporal_store(v, (float*)gx + (rb + r)*G4 + g);
        else
          __builtin_nontemporal_store(f2b(v), (u16*)gx + (rb + r)*G4 + g);
      }
    }
  }
}

// ---------------- Phase-2 persistent scan, tagged-payload protocol ----------------
// h element = dword (bf16<<16)|tag16, tag = t+1, double-buffered by t-parity.
// Writer: ONE sc0 sc1 dword store per element; no ack, no flags, no barrier.
// Reader: staging loads double as the poll. All inline-asm load results are
// consumed only after an explicit s_waitcnt + sched_barrier(0) fence (rule #18).
template<typename GT>
__global__ __launch_bounds__(256, 1) void hmlstm_scan(
    const u16* __restrict__ Whh, const GT* __restrict__ gx,
    const float* __restrict__ zpre, unsigned* __restrict__ hdw,
    float* __restrict__ out)
{
  const int tid  = threadIdx.x;
  const int lane = tid & 63, wave = tid >> 6;
  const int wg = blockIdx.x;
  const int mb = wg >> 6, hb = wg & 63;
  const int fr = lane & 15, hi4 = lane >> 4;
  const int b_l = tid >> 4, h_l = tid & 15;
  const int browg = mb*16 + b_l;

  __shared__ u16  hs[16*1024];       // 32KB, XOR-swizzled h tile
  __shared__ float glds[4][16][16];
  __shared__ float zpart[4][16];
  __shared__ u16  wz[1024];

  ((unsigned long long*)wz)[tid] = ((const unsigned long long*)(Whh + (size_t)4096*1024))[tid];

  // persistent W_hh fragments: gate row = wave*1024 + hb*16 + fr
  const int grow = wave*1024 + hb*16 + fr;
  bf16x8 Bw[32];
  #pragma unroll
  for (int kc = 0; kc < 32; ++kc)
    Bw[kc] = *(const bf16x8*)&Whh[(size_t)grow*1024 + kc*32 + hi4*8];
  #pragma unroll
  for (int kc = 0; kc < 32; ++kc)
    asm volatile("" : "+v"(Bw[kc]));

  // publish h^0 = 0 with tag 1 into parity-0 buffer (own slice)
  {
    unsigned* p = hdw + (size_t)browg*1024 + hb*16 + h_l;
    unsigned v0 = 1u;   // bf16(0)<<16 | tag 1
    asm volatile("global_store_dword %0, %1, off sc0 sc1" :: "v"(p), "v"(v0) : "memory");
  }

  float c_reg = 0.f;

  for (int t = 0; t < NT; ++t){
    const unsigned* src = hdw + (size_t)(t & 1) * 65536;
    unsigned*       dst = hdw + (size_t)((t + 1) & 1) * 65536;
    const unsigned tgt = (unsigned)(t + 1);

    // ---- staging = polling: 16 dwordx4 chunks/thread (row j, cols tid*4..+3)
    uint4 v[16];
    #pragma unroll
    for (int j = 0; j < 16; ++j){
      const uint4* p = (const uint4*)(src + (size_t)(mb*16 + j)*1024 + tid*4);
      asm volatile("global_load_dwordx4 %0, %1, off sc0 sc1" : "=v"(v[j]) : "v"(p) : "memory");
    }
    // gx + zpre issued AFTER chunks (so vmcnt(5) leaves exactly these pending)
    float gxl[4]; float zpc;
    {
      const GT* gp = gx + ((size_t)t*64 + mb*16 + hi4*4)*G4 + wave*1024 + hb*16 + fr;
      if constexpr (sizeof(GT) == 4){
        #pragma unroll
        for (int r = 0; r < 4; ++r)
          asm volatile("global_load_dword %0, %1, off nt" : "=v"(gxl[r]) : "v"((const float*)gp + (size_t)r*G4) : "memory");
      } else {
        #pragma unroll
        for (int r = 0; r < 4; ++r)
          asm volatile("global_load_ushort %0, %1, off nt" : "=v"(*(unsigned*)&gxl[r]) : "v"((const u16*)gp + (size_t)r*G4) : "memory");
      }
      asm volatile("global_load_dword %0, %1, off" : "=v"(zpc) : "v"(zpre + t*64 + browg) : "memory");
    }
    asm volatile("s_waitcnt vmcnt(5)" ::: "memory");
    __builtin_amdgcn_sched_barrier(0);

    unsigned pend = 0;
    #pragma unroll
    for (int j = 0; j < 16; ++j){
      bool ok = ((v[j].x & 0xFFFFu) == tgt) & ((v[j].y & 0xFFFFu) == tgt)
              & ((v[j].z & 0xFFFFu) == tgt) & ((v[j].w & 0xFFFFu) == tgt);
      pend |= ok ? 0u : (1u << j);
    }
    while (__any((int)(pend != 0u))){
      #pragma unroll
      for (int j = 0; j < 16; ++j){
        if (__any((int)((pend >> j) & 1u))){
          const uint4* p = (const uint4*)(src + (size_t)(mb*16 + j)*1024 + tid*4);
          asm volatile("global_load_dwordx4 %0, %1, off sc0 sc1" : "=v"(v[j]) : "v"(p) : "memory");
        }
      }
      asm volatile("s_waitcnt vmcnt(0)" ::: "memory");
      __builtin_amdgcn_sched_barrier(0);
      #pragma unroll
      for (int j = 0; j < 16; ++j){
        if ((pend >> j) & 1u){
          bool ok = ((v[j].x & 0xFFFFu) == tgt) & ((v[j].y & 0xFFFFu) == tgt)
                  & ((v[j].z & 0xFFFFu) == tgt) & ((v[j].w & 0xFFFFu) == tgt);
          if (ok) pend &= ~(1u << j);
        }
      }
    }

    // ---- strip tags, pack to bf16 pairs, swizzled LDS write (row j, col tid*4)
    #pragma unroll
    for (int j = 0; j < 16; ++j){
      unsigned p0 = (v[j].x >> 16) | (v[j].y & 0xFFFF0000u);
      unsigned p1 = (v[j].z >> 16) | (v[j].w & 0xFFFF0000u);
      uint2 pw = {p0, p1};
      int addr = j*2048 + ((((tid>>1)*16) ^ ((j&7)<<4)) + (tid&1)*8);
      *(uint2*)((char*)hs + addr) = pw;
    }
    __syncthreads();

    // ---- recurrent GEMM: 16 batches x 16 gate cols, K=1024
    f32x4 acc[4] = {}, az = {};
    #pragma unroll
    for (int kc = 0; kc < 32; ++kc){
      bf16x8 a = *(const bf16x8*)((char*)hs + fr*2048 + ((kc*64 + hi4*16) ^ ((fr&7)<<4)));
      acc[kc & 3] = __builtin_amdgcn_mfma_f32_16x16x32_bf16(a, Bw[kc], acc[kc & 3], 0, 0, 0);
    }
    // z-gate MFMA: wave w covers kc in [w*8, w*8+8)
    #pragma unroll
    for (int q = 0; q < 8; ++q){
      int kcz = wave*8 + q;
      bf16x8 a  = *(const bf16x8*)((char*)hs + fr*2048 + ((kcz*64 + hi4*16) ^ ((fr&7)<<4)));
      bf16x8 bz = *(const bf16x8*)&wz[kcz*32 + hi4*8];
      az = __builtin_amdgcn_mfma_f32_16x16x32_bf16(a, bz, az, 0, 0, 0);
    }
    f32x4 ac = (acc[0] + acc[1]) + (acc[2] + acc[3]);

    // ---- FENCE: gx/zpre were inline-asm loads; drain them before ANY use
    // (this was the R4 bug: no vmcnt covered gxl/zpc on the no-retry path)
    asm volatile("s_waitcnt vmcnt(0)" ::: "memory");
    __builtin_amdgcn_sched_barrier(0);

    // gx convert for u16 path (no-op for f32 path)
    if constexpr (sizeof(GT) != 4){
      #pragma unroll
      for (int r = 0; r < 4; ++r)
        gxl[r] = __uint_as_float((*(unsigned*)&gxl[r]) << 16);
    }

    // ---- gates -> LDS (wave 2 = tanh, others sigmoid)
    #pragma unroll
    for (int r = 0; r < 4; ++r){
      float vv = ac[r] + gxl[r];
      float s = (wave == 2) ? ftanh(vv) : fsigmoid(vv);
      glds[wave][hi4*4 + r][fr] = s;
    }
    if (fr == 0){
      #pragma unroll
      for (int r = 0; r < 4; ++r) zpart[wave][hi4*4 + r] = az[r];
    }
    __syncthreads();

    // ---- combine: one (batch, hidden) element per thread
    float iv = glds[0][b_l][h_l], fvg = glds[1][b_l][h_l];
    float gv = glds[2][b_l][h_l], ov = glds[3][b_l][h_l];
    float zs = zpart[0][b_l] + zpart[1][b_l] + zpart[2][b_l] + zpart[3][b_l];
    float zv = fsigmoid(zpc + zs);
    float ig = iv * gv;
    float cn = zv*ig + (1.f - zv)*(fvg*c_reg + ig);
    float hv_ = ov * ftanh(cn);
    c_reg = cn;
    const int hoff = browg*1024 + hb*16 + h_l;

    // ---- PUBLISH immediately: single tagged dword, no ack, no flag
    {
      unsigned pv = ((unsigned)f2b(hv_) << 16) | (unsigned)(t + 2);
      asm volatile("global_store_dword %0, %1, off sc0 sc1" :: "v"(dst + hoff), "v"(pv) : "memory");
    }

    // off-path stores
    __builtin_nontemporal_store(hv_, out + (size_t)t*65536 + hoff);
    if (t == NT-1){
      out[(size_t)NT*65536 + hoff] = hv_;            // hT
      out[(size_t)NT*65536 + 65536 + hoff] = cn;     // cT
    }
  }
}

// ---------------- host ----------------
extern "C" void kernel_launch(void* const* d_in, const int* in_sizes, int n_in,
                              void* d_out, int out_size, void* d_ws, size_t ws_size,
                              hipStream_t stream)
{
  (void)in_sizes; (void)n_in; (void)out_size;
  const float* x    = (const float*)d_in[0];
  const float* Wih  = (const float*)d_in[1];
  const float* Whh  = (const float*)d_in[2];
  const float* b_ih = (const float*)d_in[3];
  const float* b_hh = (const float*)d_in[4];
  float* out = (float*)d_out;

  size_t off = 0;
  auto alloc = [&](size_t bytes)->void*{
    void* p = (char*)d_ws + off;
    off = (off + bytes + 255) & ~(size_t)255;
    return p;
  };
  u16*  xb    = (u16*) alloc((size_t)NTB*1024*2);
  u16*  wihb  = (u16*) alloc((size_t)4097*1024*2);
  u16*  whhb  = (u16*) alloc((size_t)4097*1024*2);
  unsigned* hdw = (unsigned*)alloc((size_t)2*65536*4);   // tagged h, 2 parities
  float* zp   = (float*)alloc((size_t)NTB*4);
  bool g32 = (ws_size >= off + (size_t)NTB*G4*4);
  void* gxp = (char*)d_ws + off;

  hipMemsetAsync(hdw, 0, (size_t)2*65536*4, stream);   // kill stale tags (replay safety)
  cvt_bf16<<<dim3(2048), dim3(256), 0, stream>>>(x,   xb,   NTB*1024/8);
  cvt_bf16<<<dim3(512),  dim3(256), 0, stream>>>(Wih, wihb, 4097*1024/8);
  cvt_bf16<<<dim3(512),  dim3(256), 0, stream>>>(Whh, whhb, 4097*1024/8);
  zpre_kernel<<<dim3(256), dim3(256), 0, stream>>>(x, Wih, b_ih, b_hh, zp);
  if (g32){
    gemm_gx<float><<<dim3(8192), dim3(256), 0, stream>>>(xb, wihb, b_ih, b_hh, (float*)gxp);
    hmlstm_scan<float><<<dim3(256), dim3(256), 0, stream>>>(whhb, (const float*)gxp, zp, hdw, out);
  } else {
    gemm_gx<u16><<<dim3(8192), dim3(256), 0, stream>>>(xb, wihb, b_ih, b_hh, (u16*)gxp);
    hmlstm_scan<u16><<<dim3(256), dim3(256), 0, stream>>>(whhb, (const u16*)gxp, zp, hdw, out);
  }
}